// Round 7
// baseline (233.767 us; speedup 1.0000x reference)
//
#include <hip/hip_runtime.h>

// VectorQuantizer: x [32,64,64,64] f32, emb [512,64] f32 -> out [32,64,64,64] f32
// R17: block-granularity lever. R13-R16 established: 512-thr blocks in the
// 128-reg band = 2 blocks/CU, and barriers/queues/reg-caps don't move it
// (reg-caps spill: R14/R15). Same reg band, 256-thr/4-wave blocks -> 4
// independent blocks/CU: phases of different blocks interleave, barrier
// tails halve. MPB=32, 4096 blocks; per wave 128 codes x 32 pixels:
// s[8][2][4] (same 64-float AGPR footprint as R12/R16), xf[2][2] held,
// ef prefetched in TWO half-screens of efr[4][2] (caps arch-reg pressure
// at R16's proven level; guards the R14/R15 hoist-spill).
// Barrier-free threshold handshake kept from R16 (pthr monotone under
// atomicMin -> stale read = larger thr = candidate superset = safe).
// Exact-score semantics unchanged from R8-R16 (absmax==0): sequential-c fmaf
// dot merged with pairwise-8 xsq, _rn combine, lexicographic (se,k) u64
// atomicMin, bit-exact emb-row gather.

#define KNUM 512
#define CDIM 64
#define MPB  32

typedef __attribute__((ext_vector_type(8))) short bf16x8;
typedef __attribute__((ext_vector_type(4))) float f32x4;

__device__ __forceinline__ unsigned f2bf(float f) {   // RNE f32->bf16
    unsigned u = __float_as_uint(f);
    return (u + 0x7FFFu + ((u >> 16) & 1u)) >> 16;
}
__device__ __forceinline__ unsigned ordf(float f) {   // total-order encode
    unsigned u = __float_as_uint(f);
    return u ^ ((unsigned)(((int)u) >> 31) | 0x80000000u);
}
__device__ __forceinline__ float ordinv(unsigned u) {
    unsigned fb = (u & 0x80000000u) ? (u ^ 0x80000000u) : ~u;
    return __uint_as_float(fb);
}

__global__ __launch_bounds__(64) void vq_prep(const float* __restrict__ emb,
                                              float* __restrict__ e_sq,
                                              unsigned* __restrict__ ebf)
{
    const int k = blockIdx.x * 64 + threadIdx.x;
    const float* e = emb + k * CDIM;
    float4 f[16];
    #pragma unroll
    for (int i = 0; i < 16; ++i) f[i] = ((const float4*)e)[i];

    float r[8];
    r[0] = __fmul_rn(f[0].x, f[0].x); r[1] = __fmul_rn(f[0].y, f[0].y);
    r[2] = __fmul_rn(f[0].z, f[0].z); r[3] = __fmul_rn(f[0].w, f[0].w);
    r[4] = __fmul_rn(f[1].x, f[1].x); r[5] = __fmul_rn(f[1].y, f[1].y);
    r[6] = __fmul_rn(f[1].z, f[1].z); r[7] = __fmul_rn(f[1].w, f[1].w);
    #pragma unroll
    for (int i = 1; i < 8; ++i) {
        const float4 a = f[2 * i], c = f[2 * i + 1];
        r[0] = __fadd_rn(r[0], __fmul_rn(a.x, a.x));
        r[1] = __fadd_rn(r[1], __fmul_rn(a.y, a.y));
        r[2] = __fadd_rn(r[2], __fmul_rn(a.z, a.z));
        r[3] = __fadd_rn(r[3], __fmul_rn(a.w, a.w));
        r[4] = __fadd_rn(r[4], __fmul_rn(c.x, c.x));
        r[5] = __fadd_rn(r[5], __fmul_rn(c.y, c.y));
        r[6] = __fadd_rn(r[6], __fmul_rn(c.z, c.z));
        r[7] = __fadd_rn(r[7], __fmul_rn(c.w, c.w));
    }
    e_sq[k] = __fadd_rn(
        __fadd_rn(__fadd_rn(r[0], r[1]), __fadd_rn(r[2], r[3])),
        __fadd_rn(__fadd_rn(r[4], r[5]), __fadd_rn(r[6], r[7])));

    // bf16(-2e): exact power-of-2 scale, products are exactly -2x original
    unsigned buf[32];
    #pragma unroll
    for (int i = 0; i < 16; ++i) {
        buf[2 * i]     = f2bf(__fmul_rn(-2.0f, f[i].x))
                       | (f2bf(__fmul_rn(-2.0f, f[i].y)) << 16);
        buf[2 * i + 1] = f2bf(__fmul_rn(-2.0f, f[i].z))
                       | (f2bf(__fmul_rn(-2.0f, f[i].w)) << 16);
    }
    uint4* dst = (uint4*)(ebf + k * 32);
    #pragma unroll
    for (int i = 0; i < 8; ++i) dst[i] = ((const uint4*)buf)[i];
}

__global__ __launch_bounds__(256, 4) void vq_main(const float* __restrict__ x,
                                                  const float* __restrict__ emb,
                                                  const float* __restrict__ e_sq,
                                                  const unsigned* __restrict__ ebf,
                                                  float* __restrict__ out)
{
    __shared__ float    xt[MPB][68];           //  8704 B exact x
    __shared__ _Float16 xbf[MPB][72];          //  4608 B bf16 x (B-frags)
    __shared__ float    axp[MPB][10];          //  1280 B |x| partials
    __shared__ float    lesq[KNUM];            //  2048 B e_sq copy
    __shared__ unsigned pthr[MPB];             //   128 B ordered screen min
    __shared__ unsigned long long bestpk[MPB]; //   256 B

    const int t    = threadIdx.x;
    const int pix0 = blockIdx.x * MPB;
    const int b    = pix0 >> 12;
    const int hw0  = pix0 & 4095;
    const float* xb = x + ((size_t)b << 18) + hw0;

    const int l    = t & 63;
    const int w    = __builtin_amdgcn_readfirstlane(t >> 6);  // wave id 0..3
    const int i15  = l & 15, quad = l >> 4;
    const int nbase = w * 128;                 // this wave's 128 codes

    // ---- stage x (HBM/L3, longest latency first) ----
    {
        const int p = t & 31, g = t >> 5;      // pixel, channel-group (8 ch)
        const float* xp = xb + ((size_t)(g * 8) << 12) + p;
        float v[8];
        #pragma unroll
        for (int j = 0; j < 8; ++j) v[j] = xp[(size_t)j << 12];

        lesq[t]       = e_sq[t];
        lesq[t + 256] = e_sq[t + 256];
        if (t < MPB) { pthr[t] = 0xFFFFFFFFu; bestpk[t] = ~0ull; }

        *(float4*)&xt[p][8 * g]     = make_float4(v[0], v[1], v[2], v[3]);
        *(float4*)&xt[p][8 * g + 4] = make_float4(v[4], v[5], v[6], v[7]);
        uint4 dp;
        dp.x = f2bf(v[0]) | (f2bf(v[1]) << 16);
        dp.y = f2bf(v[2]) | (f2bf(v[3]) << 16);
        dp.z = f2bf(v[4]) | (f2bf(v[5]) << 16);
        dp.w = f2bf(v[6]) | (f2bf(v[7]) << 16);
        *(uint4*)&xbf[p][8 * g] = dp;
        axp[p][g] = ((fabsf(v[0]) + fabsf(v[1])) + (fabsf(v[2]) + fabsf(v[3])))
                  + ((fabsf(v[4]) + fabsf(v[5])) + (fabsf(v[6]) + fabsf(v[7])));
    }
    __syncthreads();                           // B1 (only pre-gather barrier)

    // ---- pixel B-frags held in regs (2 nt tiles x 2 kc) ----
    bf16x8 xf[2][2];
    #pragma unroll
    for (int nt = 0; nt < 2; ++nt)
        #pragma unroll
        for (int kc = 0; kc < 2; ++kc)
            xf[nt][kc] = *(const bf16x8*)&xbf[nt * 16 + i15][quad * 8 + kc * 32];

    // ---- MFMA screen in two half-screens (caps arch-reg pressure) ----
    float s[8][2][4];                          // [mt][nt][r], code-major
    #pragma unroll
    for (int h = 0; h < 2; ++h) {
        bf16x8 efr[4][2];
        #pragma unroll
        for (int mtl = 0; mtl < 4; ++mtl)
            #pragma unroll
            for (int kc = 0; kc < 2; ++kc)
                efr[mtl][kc] = *(const bf16x8*)((const char*)ebf
                    + (size_t)(nbase + (h * 4 + mtl) * 16 + i15) * 128
                    + kc * 64 + quad * 16);
        #pragma unroll
        for (int nt = 0; nt < 2; ++nt)
            #pragma unroll
            for (int mtl = 0; mtl < 4; ++mtl) {
                const int mt = h * 4 + mtl;
                f32x4 acc = *(const f32x4*)&lesq[nbase + mt * 16 + quad * 4];
                acc = __builtin_amdgcn_mfma_f32_16x16x32_bf16(efr[mtl][0], xf[nt][0], acc, 0, 0, 0);
                acc = __builtin_amdgcn_mfma_f32_16x16x32_bf16(efr[mtl][1], xf[nt][1], acc, 0, 0, 0);
                #pragma unroll
                for (int r = 0; r < 4; ++r)    // code=quad*4+r(+16mt), pixel=i15(+16nt)
                    s[mt][nt][r] = acc[r];
            }
    }
    // per-pixel min over this wave's 128 codes -> shared monotone pthr
    #pragma unroll
    for (int nt = 0; nt < 2; ++nt) {
        float c[8];
        #pragma unroll
        for (int mt = 0; mt < 8; ++mt)
            c[mt] = fminf(fminf(s[mt][nt][0], s[mt][nt][1]),
                          fminf(s[mt][nt][2], s[mt][nt][3]));
        float mv = fminf(fminf(fminf(c[0], c[1]), fminf(c[2], c[3])),
                         fminf(fminf(c[4], c[5]), fminf(c[6], c[7])));
        mv = fminf(mv, __shfl_xor(mv, 16));
        mv = fminf(mv, __shfl_xor(mv, 32));
        if (quad == 0) atomicMin(&pthr[nt * 16 + i15], ordf(mv));
    }
    __threadfence_block();                     // order own atomics before reads

    // ---- detect vs stale-safe threshold + serial exact rescore ----
    {
        float tr[2];
        #pragma unroll
        for (int nt = 0; nt < 2; ++nt) {
            const int p2 = nt * 16 + i15;
            const float2 g0 = *(const float2*)&axp[p2][0];
            const float2 g1 = *(const float2*)&axp[p2][2];
            const float2 g2 = *(const float2*)&axp[p2][4];
            const float2 g3 = *(const float2*)&axp[p2][6];
            const float ax = ((g0.x + g0.y) + (g1.x + g1.y))
                           + ((g2.x + g2.y) + (g3.x + g3.y));
            const float marg = fmaf(4.0e-5f, ax, 5.0e-4f);
            tr[nt] = __fadd_rn(ordinv(pthr[p2]), marg);
        }

        unsigned long long m = 0;
        #pragma unroll
        for (int mt = 0; mt < 8; ++mt)
            #pragma unroll
            for (int nt = 0; nt < 2; ++nt)
                #pragma unroll
                for (int r = 0; r < 4; ++r)
                    if (s[mt][nt][r] < tr[nt])               // rare
                        m |= 1ull << (mt * 8 + nt * 4 + r);

        while (m) {                            // serial exact rescore
            const int bit = __builtin_ctzll(m);
            m &= m - 1;
            const int mt = bit >> 3, nt = (bit >> 2) & 1, r = bit & 3;
            const int p2 = nt * 16 + i15;                    // pixel
            const int k  = nbase + mt * 16 + quad * 4 + r;   // code
            const float* xr = &xt[p2][0];
            const float* er = emb + (size_t)k * CDIM;
            // merged single pass: xsq (pairwise-8 order) + dot (sequential
            // fmaf order) -- both bit-identical to the separate np passes
            float q[8], d;
            {
                const float4 a = *(const float4*)&xr[0];
                const float4 c = *(const float4*)&xr[4];
                const float4 ea = *(const float4*)&er[0];
                const float4 ec = *(const float4*)&er[4];
                q[0] = __fmul_rn(a.x, a.x); q[1] = __fmul_rn(a.y, a.y);
                q[2] = __fmul_rn(a.z, a.z); q[3] = __fmul_rn(a.w, a.w);
                q[4] = __fmul_rn(c.x, c.x); q[5] = __fmul_rn(c.y, c.y);
                q[6] = __fmul_rn(c.z, c.z); q[7] = __fmul_rn(c.w, c.w);
                d = fmaf(a.x, ea.x, 0.f);
                d = fmaf(a.y, ea.y, d);
                d = fmaf(a.z, ea.z, d);
                d = fmaf(a.w, ea.w, d);
                d = fmaf(c.x, ec.x, d);
                d = fmaf(c.y, ec.y, d);
                d = fmaf(c.z, ec.z, d);
                d = fmaf(c.w, ec.w, d);
            }
            #pragma unroll
            for (int i = 1; i < 8; ++i) {
                const float4 a = *(const float4*)&xr[8 * i];
                const float4 c = *(const float4*)&xr[8 * i + 4];
                const float4 ea = *(const float4*)&er[8 * i];
                const float4 ec = *(const float4*)&er[8 * i + 4];
                q[0] = __fadd_rn(q[0], __fmul_rn(a.x, a.x));
                q[1] = __fadd_rn(q[1], __fmul_rn(a.y, a.y));
                q[2] = __fadd_rn(q[2], __fmul_rn(a.z, a.z));
                q[3] = __fadd_rn(q[3], __fmul_rn(a.w, a.w));
                q[4] = __fadd_rn(q[4], __fmul_rn(c.x, c.x));
                q[5] = __fadd_rn(q[5], __fmul_rn(c.y, c.y));
                q[6] = __fadd_rn(q[6], __fmul_rn(c.z, c.z));
                q[7] = __fadd_rn(q[7], __fmul_rn(c.w, c.w));
                d = fmaf(a.x, ea.x, d);
                d = fmaf(a.y, ea.y, d);
                d = fmaf(a.z, ea.z, d);
                d = fmaf(a.w, ea.w, d);
                d = fmaf(c.x, ec.x, d);
                d = fmaf(c.y, ec.y, d);
                d = fmaf(c.z, ec.z, d);
                d = fmaf(c.w, ec.w, d);
            }
            const float xs = __fadd_rn(
                __fadd_rn(__fadd_rn(q[0], q[1]), __fadd_rn(q[2], q[3])),
                __fadd_rn(__fadd_rn(q[4], q[5]), __fadd_rn(q[6], q[7])));
            const float se = __fsub_rn(__fadd_rn(xs, lesq[k]),
                                       __fmul_rn(2.0f, d));
            const unsigned long long pkd =
                ((unsigned long long)ordf(se) << 32) | (unsigned)k;
            atomicMin(&bestpk[p2], pkd);       // lexicographic (se, k)
        }
    }
    __syncthreads();                           // B2: all rescores visible

    // ---- gather winning emb row (bit-exact) -> [B,C,H,W] ----
    {
        const int p = t & 31, cg = t >> 5;
        const int wi = (int)(bestpk[p] & 0xFFFFu);
        const float* ew = emb + (size_t)wi * CDIM + 8 * cg;
        const float4 e0 = *(const float4*)ew;
        const float4 e1 = *(const float4*)(ew + 4);
        float* ob = out + ((size_t)b << 18) + (((size_t)(8 * cg)) << 12) + hw0 + p;
        ob[(size_t)0 << 12] = e0.x;
        ob[(size_t)1 << 12] = e0.y;
        ob[(size_t)2 << 12] = e0.z;
        ob[(size_t)3 << 12] = e0.w;
        ob[(size_t)4 << 12] = e1.x;
        ob[(size_t)5 << 12] = e1.y;
        ob[(size_t)6 << 12] = e1.z;
        ob[(size_t)7 << 12] = e1.w;
    }
}

extern "C" void kernel_launch(void* const* d_in, const int* in_sizes, int n_in,
                              void* d_out, int out_size, void* d_ws, size_t ws_size,
                              hipStream_t stream)
{
    const float* x   = (const float*)d_in[0];
    const float* emb = (const float*)d_in[1];
    float* out  = (float*)d_out;
    float*    e_sq = (float*)d_ws;                 // 2 KB
    unsigned* ebf  = (unsigned*)d_ws + KNUM;       // 64 KB bf16(-2e)

    hipLaunchKernelGGL(vq_prep, dim3(KNUM / 64), dim3(64), 0, stream, emb, e_sq, ebf);
    const int nblocks = (32 * 64 * 64) / MPB;      // 4096
    hipLaunchKernelGGL(vq_main, dim3(nblocks), dim3(256), 0, stream,
                       x, emb, e_sq, ebf, out);
}

// Round 9
// 148.244 us; speedup vs baseline: 1.5769x; 1.5769x over previous
//
#include <hip/hip_runtime.h>

// VectorQuantizer: x [32,64,64,64] f32, emb [512,64] f32 -> out [32,64,64,64] f32
// R18b: retry of R18 (container infra failure, non-diagnostic) with hardened
// barriers (sched_barrier(0) fences around s_barrier per guide rule #18 --
// prevents any compiler motion of LDS ops across the inline-asm wait).
// R18 design: multi-tile software pipeline on the R12 interior (the only
// spill-free point: 64 arch + 64 acc = 128 regs; R14/R15/R17 all spilled).
//  - TPB=4 tiles/block (512 blocks): tile t+1's x-loads issue right after
//    tile t's LDS staging and stay IN FLIGHT across barriers -> HBM latency
//    hidden for tiles 1-3; efr/lesq loaded once per block (4x reuse).
//  - raw s_barrier with lgkmcnt(0)-only drain (no vmcnt(0) force-drain):
//    every cross-wave handoff (xt/xbf/axp/margl/xsql/lesq/pthr/bestpk) is
//    LDS = lgkmcnt domain; global reads read-only; in-flight v-loads are
//    own-thread (compiler inserts the RAW vmcnt before ds_write).
//  - pthr/bestpk parity double-buffers: re-init of parity p at tile t is
//    3 barriers after its last reader (gather of tile t-2).
// Screen/detect/rescore/gather bodies byte-for-byte R12 (absmax==0-validated):
// sequential-c fmaf dot, pairwise-8 xsq, _rn combine, lexicographic (se,k)
// u64 atomicMin, bit-exact emb-row gather.

#define KNUM 512
#define CDIM 64
#define MPB  64
#define TPB  4

typedef __attribute__((ext_vector_type(8))) short bf16x8;
typedef __attribute__((ext_vector_type(4))) float f32x4;

#define BARRIER() do {                                          \
    asm volatile("s_waitcnt lgkmcnt(0)" ::: "memory");          \
    __builtin_amdgcn_sched_barrier(0);                          \
    __builtin_amdgcn_s_barrier();                               \
    __builtin_amdgcn_sched_barrier(0);                          \
} while (0)

__device__ __forceinline__ unsigned f2bf(float f) {   // RNE f32->bf16
    unsigned u = __float_as_uint(f);
    return (u + 0x7FFFu + ((u >> 16) & 1u)) >> 16;
}
__device__ __forceinline__ unsigned ordf(float f) {   // total-order encode
    unsigned u = __float_as_uint(f);
    return u ^ ((unsigned)(((int)u) >> 31) | 0x80000000u);
}
__device__ __forceinline__ float ordinv(unsigned u) {
    unsigned fb = (u & 0x80000000u) ? (u ^ 0x80000000u) : ~u;
    return __uint_as_float(fb);
}

__device__ __forceinline__ float xsq_pairwise8(const float* xr)   // np order
{
    float r[8];
    {
        const float4 a = *(const float4*)&xr[0];
        const float4 c = *(const float4*)&xr[4];
        r[0] = __fmul_rn(a.x, a.x); r[1] = __fmul_rn(a.y, a.y);
        r[2] = __fmul_rn(a.z, a.z); r[3] = __fmul_rn(a.w, a.w);
        r[4] = __fmul_rn(c.x, c.x); r[5] = __fmul_rn(c.y, c.y);
        r[6] = __fmul_rn(c.z, c.z); r[7] = __fmul_rn(c.w, c.w);
    }
    #pragma unroll
    for (int i = 1; i < 8; ++i) {
        const float4 a = *(const float4*)&xr[8 * i];
        const float4 c = *(const float4*)&xr[8 * i + 4];
        r[0] = __fadd_rn(r[0], __fmul_rn(a.x, a.x));
        r[1] = __fadd_rn(r[1], __fmul_rn(a.y, a.y));
        r[2] = __fadd_rn(r[2], __fmul_rn(a.z, a.z));
        r[3] = __fadd_rn(r[3], __fmul_rn(a.w, a.w));
        r[4] = __fadd_rn(r[4], __fmul_rn(c.x, c.x));
        r[5] = __fadd_rn(r[5], __fmul_rn(c.y, c.y));
        r[6] = __fadd_rn(r[6], __fmul_rn(c.z, c.z));
        r[7] = __fadd_rn(r[7], __fmul_rn(c.w, c.w));
    }
    return __fadd_rn(
        __fadd_rn(__fadd_rn(r[0], r[1]), __fadd_rn(r[2], r[3])),
        __fadd_rn(__fadd_rn(r[4], r[5]), __fadd_rn(r[6], r[7])));
}

__global__ __launch_bounds__(64) void vq_prep(const float* __restrict__ emb,
                                              float* __restrict__ e_sq,
                                              unsigned* __restrict__ ebf)
{
    const int k = blockIdx.x * 64 + threadIdx.x;
    const float* e = emb + k * CDIM;
    float4 f[16];
    #pragma unroll
    for (int i = 0; i < 16; ++i) f[i] = ((const float4*)e)[i];

    float r[8];
    r[0] = __fmul_rn(f[0].x, f[0].x); r[1] = __fmul_rn(f[0].y, f[0].y);
    r[2] = __fmul_rn(f[0].z, f[0].z); r[3] = __fmul_rn(f[0].w, f[0].w);
    r[4] = __fmul_rn(f[1].x, f[1].x); r[5] = __fmul_rn(f[1].y, f[1].y);
    r[6] = __fmul_rn(f[1].z, f[1].z); r[7] = __fmul_rn(f[1].w, f[1].w);
    #pragma unroll
    for (int i = 1; i < 8; ++i) {
        const float4 a = f[2 * i], c = f[2 * i + 1];
        r[0] = __fadd_rn(r[0], __fmul_rn(a.x, a.x));
        r[1] = __fadd_rn(r[1], __fmul_rn(a.y, a.y));
        r[2] = __fadd_rn(r[2], __fmul_rn(a.z, a.z));
        r[3] = __fadd_rn(r[3], __fmul_rn(a.w, a.w));
        r[4] = __fadd_rn(r[4], __fmul_rn(c.x, c.x));
        r[5] = __fadd_rn(r[5], __fmul_rn(c.y, c.y));
        r[6] = __fadd_rn(r[6], __fmul_rn(c.z, c.z));
        r[7] = __fadd_rn(r[7], __fmul_rn(c.w, c.w));
    }
    e_sq[k] = __fadd_rn(
        __fadd_rn(__fadd_rn(r[0], r[1]), __fadd_rn(r[2], r[3])),
        __fadd_rn(__fadd_rn(r[4], r[5]), __fadd_rn(r[6], r[7])));

    // bf16(-2e): exact power-of-2 scale, products are exactly -2x original
    unsigned buf[32];
    #pragma unroll
    for (int i = 0; i < 16; ++i) {
        buf[2 * i]     = f2bf(__fmul_rn(-2.0f, f[i].x))
                       | (f2bf(__fmul_rn(-2.0f, f[i].y)) << 16);
        buf[2 * i + 1] = f2bf(__fmul_rn(-2.0f, f[i].z))
                       | (f2bf(__fmul_rn(-2.0f, f[i].w)) << 16);
    }
    uint4* dst = (uint4*)(ebf + k * 32);
    #pragma unroll
    for (int i = 0; i < 8; ++i) dst[i] = ((const uint4*)buf)[i];
}

__global__ __launch_bounds__(512, 4) void vq_main(const float* __restrict__ x,
                                                  const float* __restrict__ emb,
                                                  const float* __restrict__ e_sq,
                                                  const unsigned* __restrict__ ebf,
                                                  float* __restrict__ out)
{
    __shared__ float    xt[MPB][68];             // 17408 B exact x
    __shared__ _Float16 xbf[MPB][72];            //  9216 B bf16 x (B-frags)
    __shared__ float    axp[MPB][10];            //  2560 B |x| partials
    __shared__ float    margl[MPB];              //   256 B per-pixel margin
    __shared__ float    xsql[MPB];               //   256 B per-pixel ||x||^2
    __shared__ float    lesq[KNUM];              //  2048 B e_sq copy
    __shared__ unsigned pthr2[2][MPB];           //   512 B parity screen mins
    __shared__ unsigned long long bestpk2[2][MPB]; // 1024 B parity winners

    const int t    = threadIdx.x;
    const int l    = t & 63;
    const int w    = __builtin_amdgcn_readfirstlane(t >> 6);  // uniform wave id
    const int i15  = l & 15, quad = l >> 4;
    const int nbase = w * 64;
    const int pixbase = blockIdx.x * (TPB * MPB);

    // ---- prologue: issue tile-0 x loads (HBM, longest latency) ----
    float v[8];
    {
        const float* xp = x + (((size_t)(pixbase >> 12)) << 18) + (pixbase & 4095)
                        + (((size_t)(8 * w)) << 12) + l;
        #pragma unroll
        for (int j = 0; j < 8; ++j) v[j] = xp[(size_t)j << 12];
    }
    // ---- code A-frags (bf16(-2e)) loaded ONCE, reused for all tiles ----
    bf16x8 efr[4][2];
    #pragma unroll
    for (int mt = 0; mt < 4; ++mt)
        #pragma unroll
        for (int kc = 0; kc < 2; ++kc)
            efr[mt][kc] = *(const bf16x8*)((const char*)ebf
                + (size_t)(nbase + mt * 16 + i15) * 128 + kc * 64 + quad * 16);

    lesq[t] = e_sq[t];                         // KNUM == blockDim
    if (t < MPB) {
        pthr2[0][t] = 0xFFFFFFFFu; pthr2[1][t] = 0xFFFFFFFFu;
        bestpk2[0][t] = ~0ull;     bestpk2[1][t] = ~0ull;
    }

    for (int tile = 0; tile < TPB; ++tile) {
        const int par = tile & 1;
        const int pix = pixbase + tile * MPB;
        const int b   = pix >> 12;
        const int hw0 = pix & 4095;

        // re-init this parity (last read: gather of tile-2, 3 barriers ago)
        if (tile >= 2 && t < MPB) {
            pthr2[par][t] = 0xFFFFFFFFu;
            bestpk2[par][t] = ~0ull;
        }

        // ---- stage current tile from v: f32 + bf16 + |x| partial ----
        *(float4*)&xt[l][8 * w]     = make_float4(v[0], v[1], v[2], v[3]);
        *(float4*)&xt[l][8 * w + 4] = make_float4(v[4], v[5], v[6], v[7]);
        {
            uint4 dp;
            dp.x = f2bf(v[0]) | (f2bf(v[1]) << 16);
            dp.y = f2bf(v[2]) | (f2bf(v[3]) << 16);
            dp.z = f2bf(v[4]) | (f2bf(v[5]) << 16);
            dp.w = f2bf(v[6]) | (f2bf(v[7]) << 16);
            *(uint4*)&xbf[l][8 * w] = dp;
        }
        axp[l][w] = ((fabsf(v[0]) + fabsf(v[1])) + (fabsf(v[2]) + fabsf(v[3])))
                  + ((fabsf(v[4]) + fabsf(v[5])) + (fabsf(v[6]) + fabsf(v[7])));

        // ---- issue NEXT tile's loads; stay in flight across barriers ----
        if (tile + 1 < TPB) {
            const int pixn = pixbase + (tile + 1) * MPB;
            const float* xpn = x + (((size_t)(pixn >> 12)) << 18) + (pixn & 4095)
                             + (((size_t)(8 * w)) << 12) + l;
            #pragma unroll
            for (int j = 0; j < 8; ++j) v[j] = xpn[(size_t)j << 12];
        }

        BARRIER();                             // B1 (lgkmcnt-only)

        // ---- wave 0: per-pixel margin; waves 4-7: exact ||x||^2 ----
        if (t < MPB) {
            const float ax = ((axp[t][0] + axp[t][1]) + (axp[t][2] + axp[t][3]))
                           + ((axp[t][4] + axp[t][5]) + (axp[t][6] + axp[t][7]));
            margl[t] = fmaf(4.0e-5f, ax, 5.0e-4f);
        }
        if (w >= 4 && l < 16) {                // 2-way bank alias = free
            const int p = (w - 4) * 16 + l;
            xsql[p] = xsq_pairwise8(xt[p]);
        }

        // ---- MFMA screen: D[code][pixel] = e_sq[code] + (-2e).x ----
        float s[4][4][4];                      // [mt][nt][r], code-major
        #pragma unroll
        for (int nt = 0; nt < 4; ++nt) {
            const bf16x8 xf0 = *(const bf16x8*)&xbf[nt * 16 + i15][quad * 8];
            const bf16x8 xf1 = *(const bf16x8*)&xbf[nt * 16 + i15][quad * 8 + 32];
            #pragma unroll
            for (int mt = 0; mt < 4; ++mt) {
                f32x4 acc = *(const f32x4*)&lesq[nbase + mt * 16 + quad * 4];
                acc = __builtin_amdgcn_mfma_f32_16x16x32_bf16(efr[mt][0], xf0, acc, 0, 0, 0);
                acc = __builtin_amdgcn_mfma_f32_16x16x32_bf16(efr[mt][1], xf1, acc, 0, 0, 0);
                #pragma unroll
                for (int r = 0; r < 4; ++r)    // code=quad*4+r(+16mt), pixel=i15(+16nt)
                    s[mt][nt][r] = acc[r];
            }
        }
        // per-pixel min over this wave's 64 codes: fmin tree + 2 shfl
        #pragma unroll
        for (int nt = 0; nt < 4; ++nt) {
            float mv = fminf(fminf(fminf(s[0][nt][0], s[0][nt][1]),
                                   fminf(s[0][nt][2], s[0][nt][3])),
                             fminf(fminf(s[1][nt][0], s[1][nt][1]),
                                   fminf(s[1][nt][2], s[1][nt][3])));
            mv = fminf(mv, fminf(fminf(fminf(s[2][nt][0], s[2][nt][1]),
                                       fminf(s[2][nt][2], s[2][nt][3])),
                                 fminf(fminf(s[3][nt][0], s[3][nt][1]),
                                       fminf(s[3][nt][2], s[3][nt][3]))));
            mv = fminf(mv, __shfl_xor(mv, 16));
            mv = fminf(mv, __shfl_xor(mv, 32));
            if (quad == 0) atomicMin(&pthr2[par][nt * 16 + i15], ordf(mv));
        }
        BARRIER();                             // B2 (lgkmcnt-only)

        // ---- detect + serial exact np-semantics rescore (R12 body) ----
        {
            float tr[4];
            #pragma unroll
            for (int nt = 0; nt < 4; ++nt)
                tr[nt] = __fadd_rn(ordinv(pthr2[par][nt * 16 + i15]),
                                   margl[nt * 16 + i15]);

            unsigned long long m = 0;
            #pragma unroll
            for (int mt = 0; mt < 4; ++mt)
                #pragma unroll
                for (int nt = 0; nt < 4; ++nt)
                    #pragma unroll
                    for (int r = 0; r < 4; ++r)
                        if (s[mt][nt][r] < tr[nt])           // rare
                            m |= 1ull << (mt * 16 + nt * 4 + r);

            while (m) {
                const int bit = __builtin_ctzll(m);
                m &= m - 1;
                const int mt = bit >> 4, nt = (bit >> 2) & 3, r = bit & 3;
                const int p2 = nt * 16 + i15;                    // pixel
                const int k  = nbase + mt * 16 + quad * 4 + r;   // code
                const float xs = xsql[p2];
                const float* er = emb + (size_t)k * CDIM;
                float d = 0.f;
                #pragma unroll
                for (int c4 = 0; c4 < 16; ++c4) {  // sequential-c fmaf = np order
                    const float4 xv = *(const float4*)&xt[p2][4 * c4];
                    const float4 ev = *(const float4*)&er[4 * c4];
                    d = fmaf(xv.x, ev.x, d);
                    d = fmaf(xv.y, ev.y, d);
                    d = fmaf(xv.z, ev.z, d);
                    d = fmaf(xv.w, ev.w, d);
                }
                const float se = __fsub_rn(__fadd_rn(xs, lesq[k]),
                                           __fmul_rn(2.0f, d));
                const unsigned long long pkd =
                    ((unsigned long long)ordf(se) << 32) | (unsigned)k;
                atomicMin(&bestpk2[par][p2], pkd);   // lexicographic (se, k)
            }
        }
        BARRIER();                             // B3 (lgkmcnt-only)

        // ---- gather winning emb row (bit-exact) -> [B,C,H,W] ----
        {
            const int wi = (int)(bestpk2[par][l] & 0xFFFFu);
            const float* ew = emb + (size_t)wi * CDIM + 8 * w;
            const float4 e0 = *(const float4*)ew;
            const float4 e1 = *(const float4*)(ew + 4);
            float* ob = out + ((size_t)b << 18) + (((size_t)(8 * w)) << 12) + hw0 + l;
            ob[(size_t)0 << 12] = e0.x;
            ob[(size_t)1 << 12] = e0.y;
            ob[(size_t)2 << 12] = e0.z;
            ob[(size_t)3 << 12] = e0.w;
            ob[(size_t)4 << 12] = e1.x;
            ob[(size_t)5 << 12] = e1.y;
            ob[(size_t)6 << 12] = e1.z;
            ob[(size_t)7 << 12] = e1.w;
        }
    }
}

extern "C" void kernel_launch(void* const* d_in, const int* in_sizes, int n_in,
                              void* d_out, int out_size, void* d_ws, size_t ws_size,
                              hipStream_t stream)
{
    const float* x   = (const float*)d_in[0];
    const float* emb = (const float*)d_in[1];
    float* out  = (float*)d_out;
    float*    e_sq = (float*)d_ws;                 // 2 KB
    unsigned* ebf  = (unsigned*)d_ws + KNUM;       // 64 KB bf16(-2e)

    hipLaunchKernelGGL(vq_prep, dim3(KNUM / 64), dim3(64), 0, stream, emb, e_sq, ebf);
    const int nblocks = (32 * 64 * 64) / (MPB * TPB);  // 512
    hipLaunchKernelGGL(vq_main, dim3(nblocks), dim3(512), 0, stream,
                       x, emb, e_sq, ebf, out);
}

// Round 10
// 119.487 us; speedup vs baseline: 1.9564x; 1.2407x over previous
//
#include <hip/hip_runtime.h>

// VectorQuantizer: x [32,64,64,64] f32, emb [512,64] f32 -> out [32,64,64,64] f32
// R19: restore the Round-2 champion (51.3us main, the ONLY spill-free point:
// 64 arch + 64 acc regs; R14/R15/R17/R18b all spilled when restructured) plus
// bit-exact zero-register micro-cuts:
//  - min3-fusable fmin chains in the fold (clang -> v_min3_f32; exact, no NaNs)
//  - xsql computed by waves 4-7 (16 lanes each; proven in R14/R15) instead of
//    wave 0 -> wave 0's path to its atomicMin is ~130 VALU shorter
//  - nontemporal stores for out (write-only; keeps L2/L3 for x, which is
//    L3-resident)
// Structure: R12 swapped screen (A=codes bf16(-2e), B=pixels, C-init=e_sq),
// scores held in acc regs, 3-barrier threshold handshake, margin-gated
// per-element detect, serial exact rescore.
// Exact-score semantics (absmax==0-validated): sequential-c fmaf dot,
// pairwise-8 xsq, _rn combine, lexicographic (se,k) u64 atomicMin, bit-exact
// emb-row gather.

#define KNUM 512
#define CDIM 64
#define MPB  64

typedef __attribute__((ext_vector_type(8))) short bf16x8;
typedef __attribute__((ext_vector_type(4))) float f32x4;

__device__ __forceinline__ unsigned f2bf(float f) {   // RNE f32->bf16
    unsigned u = __float_as_uint(f);
    return (u + 0x7FFFu + ((u >> 16) & 1u)) >> 16;
}
__device__ __forceinline__ unsigned ordf(float f) {   // total-order encode
    unsigned u = __float_as_uint(f);
    return u ^ ((unsigned)(((int)u) >> 31) | 0x80000000u);
}
__device__ __forceinline__ float ordinv(unsigned u) {
    unsigned fb = (u & 0x80000000u) ? (u ^ 0x80000000u) : ~u;
    return __uint_as_float(fb);
}

__device__ __forceinline__ float xsq_pairwise8(const float* xr)   // np order
{
    float r[8];
    {
        const float4 a = *(const float4*)&xr[0];
        const float4 c = *(const float4*)&xr[4];
        r[0] = __fmul_rn(a.x, a.x); r[1] = __fmul_rn(a.y, a.y);
        r[2] = __fmul_rn(a.z, a.z); r[3] = __fmul_rn(a.w, a.w);
        r[4] = __fmul_rn(c.x, c.x); r[5] = __fmul_rn(c.y, c.y);
        r[6] = __fmul_rn(c.z, c.z); r[7] = __fmul_rn(c.w, c.w);
    }
    #pragma unroll
    for (int i = 1; i < 8; ++i) {
        const float4 a = *(const float4*)&xr[8 * i];
        const float4 c = *(const float4*)&xr[8 * i + 4];
        r[0] = __fadd_rn(r[0], __fmul_rn(a.x, a.x));
        r[1] = __fadd_rn(r[1], __fmul_rn(a.y, a.y));
        r[2] = __fadd_rn(r[2], __fmul_rn(a.z, a.z));
        r[3] = __fadd_rn(r[3], __fmul_rn(a.w, a.w));
        r[4] = __fadd_rn(r[4], __fmul_rn(c.x, c.x));
        r[5] = __fadd_rn(r[5], __fmul_rn(c.y, c.y));
        r[6] = __fadd_rn(r[6], __fmul_rn(c.z, c.z));
        r[7] = __fadd_rn(r[7], __fmul_rn(c.w, c.w));
    }
    return __fadd_rn(
        __fadd_rn(__fadd_rn(r[0], r[1]), __fadd_rn(r[2], r[3])),
        __fadd_rn(__fadd_rn(r[4], r[5]), __fadd_rn(r[6], r[7])));
}

__global__ __launch_bounds__(64) void vq_prep(const float* __restrict__ emb,
                                              float* __restrict__ e_sq,
                                              unsigned* __restrict__ ebf)
{
    const int k = blockIdx.x * 64 + threadIdx.x;
    const float* e = emb + k * CDIM;
    float4 f[16];
    #pragma unroll
    for (int i = 0; i < 16; ++i) f[i] = ((const float4*)e)[i];

    float r[8];
    r[0] = __fmul_rn(f[0].x, f[0].x); r[1] = __fmul_rn(f[0].y, f[0].y);
    r[2] = __fmul_rn(f[0].z, f[0].z); r[3] = __fmul_rn(f[0].w, f[0].w);
    r[4] = __fmul_rn(f[1].x, f[1].x); r[5] = __fmul_rn(f[1].y, f[1].y);
    r[6] = __fmul_rn(f[1].z, f[1].z); r[7] = __fmul_rn(f[1].w, f[1].w);
    #pragma unroll
    for (int i = 1; i < 8; ++i) {
        const float4 a = f[2 * i], c = f[2 * i + 1];
        r[0] = __fadd_rn(r[0], __fmul_rn(a.x, a.x));
        r[1] = __fadd_rn(r[1], __fmul_rn(a.y, a.y));
        r[2] = __fadd_rn(r[2], __fmul_rn(a.z, a.z));
        r[3] = __fadd_rn(r[3], __fmul_rn(a.w, a.w));
        r[4] = __fadd_rn(r[4], __fmul_rn(c.x, c.x));
        r[5] = __fadd_rn(r[5], __fmul_rn(c.y, c.y));
        r[6] = __fadd_rn(r[6], __fmul_rn(c.z, c.z));
        r[7] = __fadd_rn(r[7], __fmul_rn(c.w, c.w));
    }
    e_sq[k] = __fadd_rn(
        __fadd_rn(__fadd_rn(r[0], r[1]), __fadd_rn(r[2], r[3])),
        __fadd_rn(__fadd_rn(r[4], r[5]), __fadd_rn(r[6], r[7])));

    // bf16(-2e): exact power-of-2 scale, products are exactly -2x original
    unsigned buf[32];
    #pragma unroll
    for (int i = 0; i < 16; ++i) {
        buf[2 * i]     = f2bf(__fmul_rn(-2.0f, f[i].x))
                       | (f2bf(__fmul_rn(-2.0f, f[i].y)) << 16);
        buf[2 * i + 1] = f2bf(__fmul_rn(-2.0f, f[i].z))
                       | (f2bf(__fmul_rn(-2.0f, f[i].w)) << 16);
    }
    uint4* dst = (uint4*)(ebf + k * 32);
    #pragma unroll
    for (int i = 0; i < 8; ++i) dst[i] = ((const uint4*)buf)[i];
}

__global__ __launch_bounds__(512, 4) void vq_main(const float* __restrict__ x,
                                                  const float* __restrict__ emb,
                                                  const float* __restrict__ e_sq,
                                                  const unsigned* __restrict__ ebf,
                                                  float* __restrict__ out)
{
    __shared__ float    xt[MPB][68];           // 17408 B exact x
    __shared__ _Float16 xbf[MPB][72];          //  9216 B bf16 x (B-frags)
    __shared__ float    axp[MPB][10];          //  2560 B |x| partials
    __shared__ float    margl[MPB];            //   256 B per-pixel margin
    __shared__ float    xsql[MPB];             //   256 B per-pixel ||x||^2
    __shared__ unsigned pthr[MPB];             //   256 B ordered screen min
    __shared__ unsigned long long bestpk[MPB]; //   512 B

    const int t    = threadIdx.x;
    const int pix0 = blockIdx.x * MPB;
    const int b    = pix0 >> 12;
    const int hw0  = pix0 & 4095;
    const float* xb = x + ((size_t)b << 18) + hw0;

    const int l    = t & 63;
    const int w    = __builtin_amdgcn_readfirstlane(t >> 6);  // uniform wave id
    const int i15  = l & 15, quad = l >> 4;
    const int nbase = w * 64;

    // ---- issue x staging loads first (HBM/L3, longest latency) ----
    const float* xp = xb + ((size_t)(8 * w) << 12) + l;
    float v[8];
    #pragma unroll
    for (int j = 0; j < 8; ++j) v[j] = xp[(size_t)j << 12];

    // ---- prefetch code A-frags (bf16(-2e)) + e_sq C-inits (L2) ----
    bf16x8 efr[4][2];
    #pragma unroll
    for (int mt = 0; mt < 4; ++mt)
        #pragma unroll
        for (int kc = 0; kc < 2; ++kc)
            efr[mt][kc] = *(const bf16x8*)((const char*)ebf
                + (size_t)(nbase + mt * 16 + i15) * 128 + kc * 64 + quad * 16);
    f32x4 esql[4];
    #pragma unroll
    for (int mt = 0; mt < 4; ++mt)
        esql[mt] = *(const f32x4*)(e_sq + nbase + mt * 16 + quad * 4);

    if (t < MPB) { pthr[t] = 0xFFFFFFFFu; bestpk[t] = ~0ull; }

    // ---- finish staging: f32 + bf16 + |x| partial ----
    {
        *(float4*)&xt[l][8 * w]     = make_float4(v[0], v[1], v[2], v[3]);
        *(float4*)&xt[l][8 * w + 4] = make_float4(v[4], v[5], v[6], v[7]);
        uint4 dp;
        dp.x = f2bf(v[0]) | (f2bf(v[1]) << 16);
        dp.y = f2bf(v[2]) | (f2bf(v[3]) << 16);
        dp.z = f2bf(v[4]) | (f2bf(v[5]) << 16);
        dp.w = f2bf(v[6]) | (f2bf(v[7]) << 16);
        *(uint4*)&xbf[l][8 * w] = dp;
        axp[l][w] = ((fabsf(v[0]) + fabsf(v[1])) + (fabsf(v[2]) + fabsf(v[3])))
                  + ((fabsf(v[4]) + fabsf(v[5])) + (fabsf(v[6]) + fabsf(v[7])));
    }
    __syncthreads();

    // ---- wave 0: per-pixel margin (cheap); waves 4-7: exact ||x||^2 ----
    if (t < MPB) {
        const float ax = ((axp[t][0] + axp[t][1]) + (axp[t][2] + axp[t][3]))
                       + ((axp[t][4] + axp[t][5]) + (axp[t][6] + axp[t][7]));
        margl[t] = fmaf(4.0e-5f, ax, 5.0e-4f);
    }
    if (w >= 4 && l < 16) {                    // 2-way bank alias = free
        const int p = (w - 4) * 16 + l;
        xsql[p] = xsq_pairwise8(xt[p]);
    }

    // ---- MFMA screen: D[code][pixel] = e_sq[code] + (-2e).x ----
    float s[4][4][4];                          // [mt][nt][r], code-major
    #pragma unroll
    for (int nt = 0; nt < 4; ++nt) {
        const bf16x8 xf0 = *(const bf16x8*)&xbf[nt * 16 + i15][quad * 8];
        const bf16x8 xf1 = *(const bf16x8*)&xbf[nt * 16 + i15][quad * 8 + 32];
        #pragma unroll
        for (int mt = 0; mt < 4; ++mt) {
            f32x4 acc = esql[mt];              // C-init = e_sq[code row]
            acc = __builtin_amdgcn_mfma_f32_16x16x32_bf16(efr[mt][0], xf0, acc, 0, 0, 0);
            acc = __builtin_amdgcn_mfma_f32_16x16x32_bf16(efr[mt][1], xf1, acc, 0, 0, 0);
            #pragma unroll
            for (int r = 0; r < 4; ++r)        // code=quad*4+r(+16mt), pixel=i15(+16nt)
                s[mt][nt][r] = acc[r];
        }
    }
    // per-pixel min over this wave's 64 codes (min3-fusable 3-chains) + 2 shfl
    #pragma unroll
    for (int nt = 0; nt < 4; ++nt) {
        float mm[4];
        #pragma unroll
        for (int mt = 0; mt < 4; ++mt)
            mm[mt] = fminf(fminf(fminf(s[mt][nt][0], s[mt][nt][1]),
                                 s[mt][nt][2]), s[mt][nt][3]);
        float mv = fminf(fminf(fminf(mm[0], mm[1]), mm[2]), mm[3]);
        mv = fminf(mv, __shfl_xor(mv, 16));
        mv = fminf(mv, __shfl_xor(mv, 32));
        if (quad == 0) atomicMin(&pthr[nt * 16 + i15], ordf(mv));
    }
    __syncthreads();

    // ---- candidate detect + inline exact np-semantics rescore ----
    {
        float tr[4];
        #pragma unroll
        for (int nt = 0; nt < 4; ++nt)
            tr[nt] = __fadd_rn(ordinv(pthr[nt * 16 + i15]),
                               margl[nt * 16 + i15]);

        unsigned long long m = 0;
        #pragma unroll
        for (int mt = 0; mt < 4; ++mt)
            #pragma unroll
            for (int nt = 0; nt < 4; ++nt)
                #pragma unroll
                for (int r = 0; r < 4; ++r)
                    if (s[mt][nt][r] < tr[nt])               // rare
                        m |= 1ull << (mt * 16 + nt * 4 + r);

        while (m) {                                          // serial rescore
            const int bit = __builtin_ctzll(m);
            m &= m - 1;
            const int mt = bit >> 4, nt = (bit >> 2) & 3, r = bit & 3;
            const int p2 = nt * 16 + i15;                    // pixel
            const int k  = nbase + mt * 16 + quad * 4 + r;   // code
            const float xs = xsql[p2];
            const float* er = emb + (size_t)k * CDIM;
            float d = 0.f;
            #pragma unroll
            for (int c4 = 0; c4 < 16; ++c4) {    // sequential-c fmaf = np order
                const float4 xv = *(const float4*)&xt[p2][4 * c4];
                const float4 ev = *(const float4*)&er[4 * c4];
                d = fmaf(xv.x, ev.x, d);
                d = fmaf(xv.y, ev.y, d);
                d = fmaf(xv.z, ev.z, d);
                d = fmaf(xv.w, ev.w, d);
            }
            const float se = __fsub_rn(__fadd_rn(xs, e_sq[k]),
                                       __fmul_rn(2.0f, d));
            const unsigned long long pkd =
                ((unsigned long long)ordf(se) << 32) | (unsigned)k;
            atomicMin(&bestpk[p2], pkd);         // lexicographic (se, k)
        }
    }
    __syncthreads();

    // ---- gather winning emb row (bit-exact) -> [B,C,H,W], nt stores ----
    {
        const int wi = (int)(bestpk[l] & 0xFFFFu);
        const float* ew = emb + (size_t)wi * CDIM + 8 * w;
        const float4 e0 = *(const float4*)ew;
        const float4 e1 = *(const float4*)(ew + 4);
        float* ob = out + ((size_t)b << 18) + (((size_t)(8 * w)) << 12) + hw0 + l;
        __builtin_nontemporal_store(e0.x, &ob[(size_t)0 << 12]);
        __builtin_nontemporal_store(e0.y, &ob[(size_t)1 << 12]);
        __builtin_nontemporal_store(e0.z, &ob[(size_t)2 << 12]);
        __builtin_nontemporal_store(e0.w, &ob[(size_t)3 << 12]);
        __builtin_nontemporal_store(e1.x, &ob[(size_t)4 << 12]);
        __builtin_nontemporal_store(e1.y, &ob[(size_t)5 << 12]);
        __builtin_nontemporal_store(e1.z, &ob[(size_t)6 << 12]);
        __builtin_nontemporal_store(e1.w, &ob[(size_t)7 << 12]);
    }
}

extern "C" void kernel_launch(void* const* d_in, const int* in_sizes, int n_in,
                              void* d_out, int out_size, void* d_ws, size_t ws_size,
                              hipStream_t stream)
{
    const float* x   = (const float*)d_in[0];
    const float* emb = (const float*)d_in[1];
    float* out  = (float*)d_out;
    float*    e_sq = (float*)d_ws;                 // 2 KB
    unsigned* ebf  = (unsigned*)d_ws + KNUM;       // 64 KB bf16(-2e)

    hipLaunchKernelGGL(vq_prep, dim3(KNUM / 64), dim3(64), 0, stream, emb, e_sq, ebf);
    const int nblocks = (32 * 64 * 64) / MPB;      // 2048
    hipLaunchKernelGGL(vq_main, dim3(nblocks), dim3(512), 0, stream,
                       x, emb, e_sq, ebf, out);
}